// Round 3
// baseline (74.707 us; speedup 1.0000x reference)
//
#include <hip/hip_runtime.h>
#include <hip/hip_bf16.h>

// Problem constants (fixed by setup_inputs)
#define M_PTS   1024
#define B_SZ    2
#define NC      64
#define KS      13
#define NA      20
#define DIM_OUT 64

#define NBLK_PER_C 5           // a-slices per center
#define A_SLICE    4           // NA / NBLK_PER_C
#define NITEMS     (KS * A_SLICE)   // 52 items per block, one per lane

static constexpr float R2    = 0.4f * 0.4f;                          // 0.16
static constexpr float C2SIG = 6.25f * 1.44269504088896340736f;      // (1/(2*sigma)) * log2(e)

__global__ __launch_bounds__(64)
void KernelPropagation_24206435681031_kernel(const float* __restrict__ frag,    // (M,3)
                                             const float* __restrict__ clouds,  // (B,3,NC)
                                             const float* __restrict__ kernels, // (KS,NA,3)
                                             const float* __restrict__ W,       // (DIM_OUT,KS)
                                             float* __restrict__ out)           // (B,DIM_OUT,NC,NA)
{
    const int g  = blockIdx.x;              // 0..B*NC*NBLK_PER_C-1
    const int bc = g / NBLK_PER_C;          // center 0..127
    const int sl = g % NBLK_PER_C;          // a-slice 0..4
    const int b  = bc / NC;
    const int n  = bc % NC;
    const int t  = threadIdx.x;             // == lane (single wave)

    __shared__ float4 pf[M_PTS];            // compacted points: (x, y, z, -C*|p|^2)
    __shared__ float  accs[NITEMS];

    const float cx = clouds[(b * 3 + 0) * NC + n];
    const float cy = clouds[(b * 3 + 1) * NC + n];
    const float cz = clouds[(b * 3 + 2) * NC + n];

    // Per-lane rotated kernel point (k = t>>2, a = sl*4 + (t&3)), prescaled:
    //   w = exp2( -C|p|^2 + 2C*(p.k) - C|k|^2 ) = exp2( p.w + dot(p.xyz,k2) ) * ek
    float kx2 = 0.f, ky2 = 0.f, kz2 = 0.f, ek = 0.f;
    if (t < NITEMS) {
        const int k = t >> 2;
        const int a = sl * A_SLICE + (t & 3);
        const int ki = (k * NA + a) * 3;
        const float kx = cx + kernels[ki + 0];
        const float ky = cy + kernels[ki + 1];
        const float kz = cz + kernels[ki + 2];
        const float pn2 = kx * kx + ky * ky + kz * kz;
        ek  = exp2f(-C2SIG * pn2);
        kx2 = (2.0f * C2SIG) * kx;
        ky2 = (2.0f * C2SIG) * ky;
        kz2 = (2.0f * C2SIG) * kz;
    }

    // Ball query + compaction, single wave: ballot + register-accumulated base,
    // no atomics. M_PTS = 16 * 64 exactly, so no bounds checks.
    int wbase = 0;
    for (int base = 0; base < M_PTS; base += 64) {
        const int i = base + t;
        const float x = frag[i * 3 + 0];
        const float y = frag[i * 3 + 1];
        const float z = frag[i * 3 + 2];
        const float dx = x - cx, dy = y - cy, dz = z - cz;
        const bool in = (dx * dx + dy * dy + dz * dz) < R2;
        const unsigned long long mask = __ballot(in);
        const int pre = __popcll(mask & ((1ull << t) - 1ull));
        if (in)
            pf[wbase + pre] = make_float4(x, y, z, -C2SIG * (x * x + y * y + z * z));
        wbase += __popcll(mask);
    }
    __syncthreads();                        // single wave: barrier is ~free

    const int   npts = wbase;               // wave-uniform
    const float inv  = 1.0f / ((float)npts + 1.0f);

    // RBF accumulation: one (k,a) item per lane, broadcast LDS float4 reads.
    // Unroll-4 with two accumulators for ILP (1 wave/SIMD -> latency matters).
    float s0 = 0.f, s1 = 0.f;
    int j = 0;
    for (; j + 3 < npts; j += 4) {
        const float4 p0 = pf[j + 0];
        const float4 p1 = pf[j + 1];
        const float4 p2 = pf[j + 2];
        const float4 p3 = pf[j + 3];
        float t0 = fmaf(p0.z, kz2, fmaf(p0.y, ky2, p0.x * kx2)) + p0.w;
        float t1 = fmaf(p1.z, kz2, fmaf(p1.y, ky2, p1.x * kx2)) + p1.w;
        float t2 = fmaf(p2.z, kz2, fmaf(p2.y, ky2, p2.x * kx2)) + p2.w;
        float t3 = fmaf(p3.z, kz2, fmaf(p3.y, ky2, p3.x * kx2)) + p3.w;
        s0 = fmaf(ek, exp2f(t0), s0);
        s1 = fmaf(ek, exp2f(t1), s1);
        s0 = fmaf(ek, exp2f(t2), s0);
        s1 = fmaf(ek, exp2f(t3), s1);
    }
    for (; j < npts; ++j) {
        const float4 p0 = pf[j];
        float t0 = fmaf(p0.z, kz2, fmaf(p0.y, ky2, p0.x * kx2)) + p0.w;
        s0 = fmaf(ek, exp2f(t0), s0);
    }
    if (t < NITEMS) accs[t] = (s0 + s1) * inv;   // accs[k*4 + j]
    __syncthreads();

    // Epilogue: lane t = output channel o. out[b,o,n, sl*4 .. sl*4+3]
    //   f[j] = sum_k W[o,k] * accs[k*4+j]  -- accs reads are wave-broadcast.
    float f0 = 0.f, f1 = 0.f, f2 = 0.f, f3 = 0.f;
#pragma unroll
    for (int k = 0; k < KS; ++k) {
        const float w = W[t * KS + k];
        f0 = fmaf(w, accs[k * 4 + 0], f0);
        f1 = fmaf(w, accs[k * 4 + 1], f1);
        f2 = fmaf(w, accs[k * 4 + 2], f2);
        f3 = fmaf(w, accs[k * 4 + 3], f3);
    }
    // row stride NA*4B = 80B and sl*A_SLICE*4B = 16B multiples -> 16B aligned
    float4* dst = (float4*)(out + ((size_t)(b * DIM_OUT + t) * NC + n) * NA + sl * A_SLICE);
    *dst = make_float4(f0, f1, f2, f3);
}

extern "C" void kernel_launch(void* const* d_in, const int* in_sizes, int n_in,
                              void* d_out, int out_size, void* d_ws, size_t ws_size,
                              hipStream_t stream) {
    const float* frag    = (const float*)d_in[0];   // (1024,3)
    const float* clouds  = (const float*)d_in[1];   // (2,3,64)
    const float* kernels = (const float*)d_in[2];   // (13,20,3)
    const float* W       = (const float*)d_in[3];   // (64,13)
    float* out = (float*)d_out;                     // (2,64,64,20)

    (void)in_sizes; (void)n_in; (void)out_size; (void)d_ws; (void)ws_size;

    KernelPropagation_24206435681031_kernel<<<B_SZ * NC * NBLK_PER_C, 64, 0, stream>>>(
        frag, clouds, kernels, W, out);
}

// Round 4
// 64.646 us; speedup vs baseline: 1.1556x; 1.1556x over previous
//
#include <hip/hip_runtime.h>
#include <hip/hip_bf16.h>

// Problem constants (fixed by setup_inputs)
#define M_PTS   1024
#define B_SZ    2
#define NC      64
#define KS      13
#define NA      20
#define DIM_OUT 64

#define NBLK_PER_C 5                 // a-slices per center
#define A_SLICE    4                 // NA / NBLK_PER_C
#define NITEMS     (KS * A_SLICE)    // 52 (k,a) items per block
#define NWAVES     4
#define NTHREADS   (NWAVES * 64)     // 256

static constexpr float R2    = 0.4f * 0.4f;                          // 0.16
static constexpr float C2SIG = 6.25f * 1.44269504088896340736f;      // (1/(2*sigma)) * log2(e)

__global__ __launch_bounds__(NTHREADS)
void KernelPropagation_24206435681031_kernel(const float* __restrict__ frag,    // (M,3)
                                             const float* __restrict__ clouds,  // (B,3,NC)
                                             const float* __restrict__ kernels, // (KS,NA,3)
                                             const float* __restrict__ W,       // (DIM_OUT,KS)
                                             float* __restrict__ out)           // (B,DIM_OUT,NC,NA)
{
    const int g    = blockIdx.x;             // 0..B*NC*NBLK_PER_C-1
    const int bc   = g / NBLK_PER_C;         // center 0..127
    const int sl   = g % NBLK_PER_C;         // a-slice 0..4
    const int b    = bc / NC;
    const int n    = bc % NC;
    const int t    = threadIdx.x;
    const int lane = t & 63;
    const int w    = t >> 6;                 // wave id 0..3

    __shared__ float4 pf[M_PTS];             // compacted points: (x, y, z, -C*|p|^2)
    __shared__ float  part[NWAVES * NITEMS]; // per-quarter partial sums
    __shared__ float  accs[NITEMS];
    __shared__ int    cnt;

    const float cx = clouds[(b * 3 + 0) * NC + n];
    const float cy = clouds[(b * 3 + 1) * NC + n];
    const float cz = clouds[(b * 3 + 2) * NC + n];

    if (t == 0) cnt = 0;
    __syncthreads();

    // ---- Ball query + compaction: 4 waves x 4 chunks, ballot + 1 LDS atomic/chunk
#pragma unroll
    for (int c4 = 0; c4 < 4; ++c4) {
        const int i = (w + 4 * c4) * 64 + lane;      // chunk = w + 4*c4
        const float x = frag[i * 3 + 0];
        const float y = frag[i * 3 + 1];
        const float z = frag[i * 3 + 2];
        const float dx = x - cx, dy = y - cy, dz = z - cz;
        const bool in = (dx * dx + dy * dy + dz * dz) < R2;
        const unsigned long long mask = __ballot(in);
        const int tot = __popcll(mask);
        const int pre = __popcll(mask & ((1ull << lane) - 1ull));
        int base = 0;
        if (lane == 0 && tot) base = atomicAdd(&cnt, tot);
        base = __shfl(base, 0, 64);
        if (in)
            pf[base + pre] = make_float4(x, y, z, -C2SIG * (x * x + y * y + z * z));
    }
    __syncthreads();

    const int   npts = cnt;
    const float inv  = 1.0f / ((float)npts + 1.0f);

    // ---- RBF: item = lane (<52), point-quarter = wave id
    const int  item   = lane;
    const bool active = item < NITEMS;
    float kx2 = 0.f, ky2 = 0.f, kz2 = 0.f, ek = 0.f;
    if (active) {
        const int k  = item >> 2;
        const int a  = sl * A_SLICE + (item & 3);
        const int ki = (k * NA + a) * 3;
        const float kx = cx + kernels[ki + 0];
        const float ky = cy + kernels[ki + 1];
        const float kz = cz + kernels[ki + 2];
        ek  = exp2f(-C2SIG * (kx * kx + ky * ky + kz * kz));
        kx2 = (2.0f * C2SIG) * kx;
        ky2 = (2.0f * C2SIG) * ky;
        kz2 = (2.0f * C2SIG) * kz;
    }

    const int jlo = (npts * w)     >> 2;
    const int jhi = (npts * (w+1)) >> 2;

    float s0 = 0.f, s1 = 0.f;
    int j = jlo;
    for (; j + 3 < jhi; j += 4) {
        const float4 p0 = pf[j + 0];
        const float4 p1 = pf[j + 1];
        const float4 p2 = pf[j + 2];
        const float4 p3 = pf[j + 3];
        float t0 = fmaf(p0.z, kz2, fmaf(p0.y, ky2, p0.x * kx2)) + p0.w;
        float t1 = fmaf(p1.z, kz2, fmaf(p1.y, ky2, p1.x * kx2)) + p1.w;
        float t2 = fmaf(p2.z, kz2, fmaf(p2.y, ky2, p2.x * kx2)) + p2.w;
        float t3 = fmaf(p3.z, kz2, fmaf(p3.y, ky2, p3.x * kx2)) + p3.w;
        s0 = fmaf(ek, exp2f(t0), s0);
        s1 = fmaf(ek, exp2f(t1), s1);
        s0 = fmaf(ek, exp2f(t2), s0);
        s1 = fmaf(ek, exp2f(t3), s1);
    }
    for (; j < jhi; ++j) {
        const float4 p0 = pf[j];
        float t0 = fmaf(p0.z, kz2, fmaf(p0.y, ky2, p0.x * kx2)) + p0.w;
        s0 = fmaf(ek, exp2f(t0), s0);
    }
    if (active) part[w * NITEMS + item] = s0 + s1;
    __syncthreads();

    // ---- Reduce quarters, normalize
    if (t < NITEMS) {
        const float s = part[t] + part[NITEMS + t] + part[2 * NITEMS + t] + part[3 * NITEMS + t];
        accs[t] = s * inv;                  // accs[k*4 + jj], jj -> a = sl*4 + jj
    }
    __syncthreads();

    // ---- Epilogue: 256 outputs for this slice, one per thread.
    //      o = t>>2, jj = t&3:  out[b,o,n,sl*4+jj] = sum_k W[o,k]*accs[k*4+jj]
    {
        const int o  = t >> 2;
        const int jj = t & 3;
        float f = 0.f;
#pragma unroll
        for (int k = 0; k < KS; ++k)
            f = fmaf(W[o * KS + k], accs[k * 4 + jj], f);
        out[((size_t)(b * DIM_OUT + o) * NC + n) * NA + sl * A_SLICE + jj] = f;
    }
}

extern "C" void kernel_launch(void* const* d_in, const int* in_sizes, int n_in,
                              void* d_out, int out_size, void* d_ws, size_t ws_size,
                              hipStream_t stream) {
    const float* frag    = (const float*)d_in[0];   // (1024,3)
    const float* clouds  = (const float*)d_in[1];   // (2,3,64)
    const float* kernels = (const float*)d_in[2];   // (13,20,3)
    const float* W       = (const float*)d_in[3];   // (64,13)
    float* out = (float*)d_out;                     // (2,64,64,20)

    (void)in_sizes; (void)n_in; (void)out_size; (void)d_ws; (void)ws_size;

    KernelPropagation_24206435681031_kernel<<<B_SZ * NC * NBLK_PER_C, NTHREADS, 0, stream>>>(
        frag, clouds, kernels, W, out);
}

// Round 5
// 63.806 us; speedup vs baseline: 1.1708x; 1.0132x over previous
//
#include <hip/hip_runtime.h>
#include <hip/hip_bf16.h>

// Problem constants (fixed by setup_inputs)
#define M_PTS   1024
#define B_SZ    2
#define NC      64
#define KS      13
#define NA      20
#define DIM_OUT 64

#define NBLK_PER_C 5                 // a-slices per center
#define A_SLICE    4                 // NA / NBLK_PER_C
#define NITEMS     (KS * A_SLICE)    // 52 (k,a) items per block
#define NWAVES     4
#define NTHREADS   (NWAVES * 64)     // 256

static constexpr float R2    = 0.4f * 0.4f;                          // 0.16
static constexpr float C2SIG = 6.25f * 1.44269504088896340736f;      // (1/(2*sigma)) * log2(e)

__global__ __launch_bounds__(NTHREADS)
void KernelPropagation_24206435681031_kernel(const float* __restrict__ frag,    // (M,3)
                                             const float* __restrict__ clouds,  // (B,3,NC)
                                             const float* __restrict__ kernels, // (KS,NA,3)
                                             const float* __restrict__ W,       // (DIM_OUT,KS)
                                             float* __restrict__ out)           // (B,DIM_OUT,NC,NA)
{
    const int g    = blockIdx.x;             // 0..B*NC*NBLK_PER_C-1
    const int bc   = g / NBLK_PER_C;         // center 0..127
    const int sl   = g % NBLK_PER_C;         // a-slice 0..4
    const int b    = bc / NC;
    const int n    = bc % NC;
    const int t    = threadIdx.x;
    const int lane = t & 63;
    const int w    = t >> 6;                 // wave id 0..3

    __shared__ float4 pf[M_PTS];             // compacted points: (x, y, z, -C*|p|^2)
    __shared__ float  part[NWAVES * NITEMS]; // per-quarter partial sums
    __shared__ float  accs[NITEMS];
    __shared__ int    wtot[NWAVES];          // per-wave in-ball totals

    const float cx = clouds[(b * 3 + 0) * NC + n];
    const float cy = clouds[(b * 3 + 1) * NC + n];
    const float cz = clouds[(b * 3 + 2) * NC + n];

    // ---- Compaction front-end: wave w owns points [w*256, w*256+256).
    // Lane l holds 4 points via 3 coalesced float4 loads (issued up-front,
    // no serial dependency). frag is (1024,3) floats = 768 float4s.
    const float4* fragv = (const float4*)frag;
    const int fb = w * 192 + 3 * lane;
    const float4 va = fragv[fb + 0];
    const float4 vb = fragv[fb + 1];
    const float4 vc = fragv[fb + 2];

    // ---- Hide the load latency: per-lane rotated kernel point + prescale.
    //   wgt = exp2( -C|p|^2 + 2C*(p.k) - C|k|^2 ) = exp2( p.w + dot(p.xyz,k2) ) * ek
    const int  item   = lane;
    const bool active = item < NITEMS;
    float kx2 = 0.f, ky2 = 0.f, kz2 = 0.f, ek = 0.f;
    if (active) {
        const int k  = item >> 2;
        const int a  = sl * A_SLICE + (item & 3);
        const int ki = (k * NA + a) * 3;
        const float kx = cx + kernels[ki + 0];
        const float ky = cy + kernels[ki + 1];
        const float kz = cz + kernels[ki + 2];
        ek  = exp2f(-C2SIG * (kx * kx + ky * ky + kz * kz));
        kx2 = (2.0f * C2SIG) * kx;
        ky2 = (2.0f * C2SIG) * ky;
        kz2 = (2.0f * C2SIG) * kz;
    }

    // ---- Ball test on 4 points, 4 ballots, register prefix (no atomics).
    const float x0 = va.x, y0 = va.y, z0 = va.z;
    const float x1 = va.w, y1 = vb.x, z1 = vb.y;
    const float x2 = vb.z, y2 = vb.w, z2 = vc.x;
    const float x3 = vc.y, y3 = vc.z, z3 = vc.w;

    const float dx0 = x0 - cx, dy0 = y0 - cy, dz0 = z0 - cz;
    const float dx1 = x1 - cx, dy1 = y1 - cy, dz1 = z1 - cz;
    const float dx2 = x2 - cx, dy2 = y2 - cy, dz2 = z2 - cz;
    const float dx3 = x3 - cx, dy3 = y3 - cy, dz3 = z3 - cz;

    const bool in0 = (dx0 * dx0 + dy0 * dy0 + dz0 * dz0) < R2;
    const bool in1 = (dx1 * dx1 + dy1 * dy1 + dz1 * dz1) < R2;
    const bool in2 = (dx2 * dx2 + dy2 * dy2 + dz2 * dz2) < R2;
    const bool in3 = (dx3 * dx3 + dy3 * dy3 + dz3 * dz3) < R2;

    const unsigned long long m0 = __ballot(in0);
    const unsigned long long m1 = __ballot(in1);
    const unsigned long long m2 = __ballot(in2);
    const unsigned long long m3 = __ballot(in3);

    const int c0 = __popcll(m0), c1 = __popcll(m1), c2 = __popcll(m2), c3 = __popcll(m3);
    const int tot = c0 + c1 + c2 + c3;
    if (lane == 0) wtot[w] = tot;
    __syncthreads();

    const int t0w = wtot[0], t1w = wtot[1], t2w = wtot[2], t3w = wtot[3];
    const int npts = t0w + t1w + t2w + t3w;
    int base = 0;
    if (w > 0) base += t0w;
    if (w > 1) base += t1w;
    if (w > 2) base += t2w;

    const unsigned long long below = (1ull << lane) - 1ull;
    if (in0) pf[base + __popcll(m0 & below)]
                 = make_float4(x0, y0, z0, -C2SIG * (x0 * x0 + y0 * y0 + z0 * z0));
    if (in1) pf[base + c0 + __popcll(m1 & below)]
                 = make_float4(x1, y1, z1, -C2SIG * (x1 * x1 + y1 * y1 + z1 * z1));
    if (in2) pf[base + c0 + c1 + __popcll(m2 & below)]
                 = make_float4(x2, y2, z2, -C2SIG * (x2 * x2 + y2 * y2 + z2 * z2));
    if (in3) pf[base + c0 + c1 + c2 + __popcll(m3 & below)]
                 = make_float4(x3, y3, z3, -C2SIG * (x3 * x3 + y3 * y3 + z3 * z3));
    __syncthreads();

    const float inv = 1.0f / ((float)npts + 1.0f);

    // ---- RBF: item = lane (<52), point-quarter = wave id; broadcast LDS reads.
    const int jlo = (npts * w)       >> 2;
    const int jhi = (npts * (w + 1)) >> 2;

    float s0 = 0.f, s1 = 0.f;
    int j = jlo;
    for (; j + 3 < jhi; j += 4) {
        const float4 p0 = pf[j + 0];
        const float4 p1 = pf[j + 1];
        const float4 p2 = pf[j + 2];
        const float4 p3 = pf[j + 3];
        float u0 = fmaf(p0.z, kz2, fmaf(p0.y, ky2, p0.x * kx2)) + p0.w;
        float u1 = fmaf(p1.z, kz2, fmaf(p1.y, ky2, p1.x * kx2)) + p1.w;
        float u2 = fmaf(p2.z, kz2, fmaf(p2.y, ky2, p2.x * kx2)) + p2.w;
        float u3 = fmaf(p3.z, kz2, fmaf(p3.y, ky2, p3.x * kx2)) + p3.w;
        s0 = fmaf(ek, exp2f(u0), s0);
        s1 = fmaf(ek, exp2f(u1), s1);
        s0 = fmaf(ek, exp2f(u2), s0);
        s1 = fmaf(ek, exp2f(u3), s1);
    }
    for (; j < jhi; ++j) {
        const float4 p0 = pf[j];
        float u0 = fmaf(p0.z, kz2, fmaf(p0.y, ky2, p0.x * kx2)) + p0.w;
        s0 = fmaf(ek, exp2f(u0), s0);
    }
    if (active) part[w * NITEMS + item] = s0 + s1;
    __syncthreads();

    // ---- Reduce quarters, normalize
    if (t < NITEMS) {
        const float s = part[t] + part[NITEMS + t] + part[2 * NITEMS + t] + part[3 * NITEMS + t];
        accs[t] = s * inv;                  // accs[k*4 + jj], jj -> a = sl*4 + jj
    }
    __syncthreads();

    // ---- Epilogue: 256 outputs for this slice, one per thread.
    //      o = t>>2, jj = t&3:  out[b,o,n,sl*4+jj] = sum_k W[o,k]*accs[k*4+jj]
    {
        const int o  = t >> 2;
        const int jj = t & 3;
        float f = 0.f;
#pragma unroll
        for (int k = 0; k < KS; ++k)
            f = fmaf(W[o * KS + k], accs[k * 4 + jj], f);
        out[((size_t)(b * DIM_OUT + o) * NC + n) * NA + sl * A_SLICE + jj] = f;
    }
}

extern "C" void kernel_launch(void* const* d_in, const int* in_sizes, int n_in,
                              void* d_out, int out_size, void* d_ws, size_t ws_size,
                              hipStream_t stream) {
    const float* frag    = (const float*)d_in[0];   // (1024,3)
    const float* clouds  = (const float*)d_in[1];   // (2,3,64)
    const float* kernels = (const float*)d_in[2];   // (13,20,3)
    const float* W       = (const float*)d_in[3];   // (64,13)
    float* out = (float*)d_out;                     // (2,64,64,20)

    (void)in_sizes; (void)n_in; (void)out_size; (void)d_ws; (void)ws_size;

    KernelPropagation_24206435681031_kernel<<<B_SZ * NC * NBLK_PER_C, NTHREADS, 0, stream>>>(
        frag, clouds, kernels, W, out);
}